// Round 4
// baseline (17542.030 us; speedup 1.0000x reference)
//
#include <hip/hip_runtime.h>
#include <hip/hip_bf16.h>

// ---------------------------------------------------------------------------
// AutoregressiveBeamDecoder: B=256, T=128, D=512, H=1024, NB=64, HH=8
// Round 4: split-bf16 MFMA GEMMs with
//   - activations pre-split (hi/lo bf16) by producer kernels
//   - GEMMs: no LDS, no barriers; direct global->register fragments,
//     register ping-pong prefetch; wave tile 16x64 (1 A-frag x 4 B-frags)
//   - kc fused: logits + argmax + x-build + ctx-split (4 rows/block)
// C = Ahi@Whi + Alo@Whi + Ahi@Wlo  (3x mfma_f32_16x16x32_bf16, fp32 accum)
// ---------------------------------------------------------------------------

#define TS 68          // fp32 LDS row stride (fallback path only)
constexpr int SZ = 262144;     // 256*1024
constexpr int TT = 128;        // T
constexpr int LDA_CTX = 65536; // T*D

typedef __attribute__((ext_vector_type(8))) short short8_t;
typedef __attribute__((ext_vector_type(4))) float f32x4;

// ---------------- bf16 split helpers (bit-level, RNE) ----------------------

__device__ __forceinline__ unsigned short f2bf_rne(float v) {
    unsigned u = __float_as_uint(v);
    unsigned r = u + 0x7fffu + ((u >> 16) & 1u);
    return (unsigned short)(r >> 16);
}
__device__ __forceinline__ float bfbits2f(unsigned short h) {
    return __uint_as_float(((unsigned)h) << 16);
}
__device__ __forceinline__ void split2(float v, unsigned short& h, unsigned short& l) {
    h = f2bf_rne(v);
    l = f2bf_rne(v - bfbits2f(h));
}

// ---------------- wave-level direct-frag GEMM: 16(M) x 64(N) tile ----------
// A row-major [*, lda] bf16 hi/lo; B row-major [N][K] bf16 hi/lo.
// Lane l: l15=l&15, ko=(l>>4)*8. A row = arow_base + l15, cols k0+ko..+7.
// B rows = brow_base + ni*16 + l15. K multiple of 64.

__device__ __forceinline__ void wave_gemm_16x64(
    const unsigned short* __restrict__ Ah, const unsigned short* __restrict__ Al,
    int lda, int arow_base,
    const unsigned short* __restrict__ Bh, const unsigned short* __restrict__ Bl,
    int K, int brow_base, int lane, f32x4 acc[4])
{
    const int l15 = lane & 15, ko = (lane >> 4) * 8;
    const unsigned short* pah = Ah + (size_t)(arow_base + l15) * lda + ko;
    const unsigned short* pal = Al + (size_t)(arow_base + l15) * lda + ko;
    const unsigned short* pbh[4];
    const unsigned short* pbl[4];
#pragma unroll
    for (int ni = 0; ni < 4; ++ni) {
        pbh[ni] = Bh + (size_t)(brow_base + ni * 16 + l15) * K + ko;
        pbl[ni] = Bl + (size_t)(brow_base + ni * 16 + l15) * K + ko;
    }
    short8_t a0h, a0l, b0h[4], b0l[4];
    short8_t a1h, a1l, b1h[4], b1l[4];
    a0h = *(const short8_t*)(pah);
    a0l = *(const short8_t*)(pal);
#pragma unroll
    for (int ni = 0; ni < 4; ++ni) {
        b0h[ni] = *(const short8_t*)(pbh[ni]);
        b0l[ni] = *(const short8_t*)(pbl[ni]);
    }
    for (int k0 = 0; k0 < K; k0 += 64) {
        // prefetch k0+32 into bank1
        a1h = *(const short8_t*)(pah + k0 + 32);
        a1l = *(const short8_t*)(pal + k0 + 32);
#pragma unroll
        for (int ni = 0; ni < 4; ++ni) {
            b1h[ni] = *(const short8_t*)(pbh[ni] + k0 + 32);
            b1l[ni] = *(const short8_t*)(pbl[ni] + k0 + 32);
        }
        // compute bank0 (k0)
#pragma unroll
        for (int ni = 0; ni < 4; ++ni) {
            acc[ni] = __builtin_amdgcn_mfma_f32_16x16x32_bf16(a0h, b0h[ni], acc[ni], 0, 0, 0);
            acc[ni] = __builtin_amdgcn_mfma_f32_16x16x32_bf16(a0h, b0l[ni], acc[ni], 0, 0, 0);
            acc[ni] = __builtin_amdgcn_mfma_f32_16x16x32_bf16(a0l, b0h[ni], acc[ni], 0, 0, 0);
        }
        // prefetch k0+64 into bank0
        if (k0 + 64 < K) {
            a0h = *(const short8_t*)(pah + k0 + 64);
            a0l = *(const short8_t*)(pal + k0 + 64);
#pragma unroll
            for (int ni = 0; ni < 4; ++ni) {
                b0h[ni] = *(const short8_t*)(pbh[ni] + k0 + 64);
                b0l[ni] = *(const short8_t*)(pbl[ni] + k0 + 64);
            }
        }
        // compute bank1 (k0+32)
#pragma unroll
        for (int ni = 0; ni < 4; ++ni) {
            acc[ni] = __builtin_amdgcn_mfma_f32_16x16x32_bf16(a1h, b1h[ni], acc[ni], 0, 0, 0);
            acc[ni] = __builtin_amdgcn_mfma_f32_16x16x32_bf16(a1h, b1l[ni], acc[ni], 0, 0, 0);
            acc[ni] = __builtin_amdgcn_mfma_f32_16x16x32_bf16(a1l, b1h[ni], acc[ni], 0, 0, 0);
        }
    }
}

// ---------------- fp32 tiled GEMM core (setup + fallback) ------------------

__device__ __forceinline__ void gemm_tile64(
    const float* __restrict__ A, int lda, int Mlim, int b0,
    const float* __restrict__ W, int ldw, int n0, int K,
    float* At, float* Wt, float acc[4][4])
{
    const int tid = threadIdx.x;
    const int tx = tid & 15, ty = tid >> 4;
    const int r = tid >> 2, c0 = (tid & 3) << 2;
    for (int k0 = 0; k0 < K; k0 += 16) {
        float4 av = make_float4(0.f, 0.f, 0.f, 0.f);
        if (b0 + r < Mlim)
            av = *(const float4*)(A + (size_t)(b0 + r) * lda + k0 + c0);
        float4 wv = *(const float4*)(W + (size_t)(n0 + r) * ldw + k0 + c0);
        __syncthreads();
        At[(c0+0)*TS + r] = av.x; At[(c0+1)*TS + r] = av.y;
        At[(c0+2)*TS + r] = av.z; At[(c0+3)*TS + r] = av.w;
        Wt[(c0+0)*TS + r] = wv.x; Wt[(c0+1)*TS + r] = wv.y;
        Wt[(c0+2)*TS + r] = wv.z; Wt[(c0+3)*TS + r] = wv.w;
        __syncthreads();
#pragma unroll
        for (int kk = 0; kk < 16; ++kk) {
            float4 a = *(const float4*)(At + kk*TS + ty*4);
            float4 w = *(const float4*)(Wt + kk*TS + tx*4);
            acc[0][0] += a.x*w.x; acc[0][1] += a.x*w.y; acc[0][2] += a.x*w.z; acc[0][3] += a.x*w.w;
            acc[1][0] += a.y*w.x; acc[1][1] += a.y*w.y; acc[1][2] += a.y*w.z; acc[1][3] += a.y*w.w;
            acc[2][0] += a.z*w.x; acc[2][1] += a.z*w.y; acc[2][2] += a.z*w.z; acc[2][3] += a.z*w.w;
            acc[3][0] += a.w*w.x; acc[3][1] += a.w*w.y; acc[3][2] += a.w*w.z; acc[3][3] += a.w*w.w;
        }
    }
}

// -------------------- setup kernels ----------------------------------------

__global__ void pre0_kernel(const float* __restrict__ ctx, const int* __restrict__ bh,
                            const float* __restrict__ be, float* __restrict__ A0,
                            int* __restrict__ prev)
{
    int b = blockIdx.x, tid = threadIdx.x; // blockDim 512
    float s = 0.f;
    for (int t = 0; t < TT; ++t) s += ctx[(size_t)b * LDA_CTX + t * 512 + tid];
    A0[b * 1024 + tid] = s * (1.f / 128.f);
    float s2 = 0.f;
    for (int i = 0; i < 8; ++i) s2 += be[bh[b * 8 + i] * 512 + tid];
    A0[b * 1024 + 512 + tid] = s2 * 0.125f;
    if (tid == 0) prev[b] = bh[b * 8 + 7];
}

__global__ void copy_gb_kernel(const float* g, const float* bb, float* gb)
{
    int idx = blockIdx.x * 256 + threadIdx.x; // 8 blocks
    if (idx < 1024) gb[idx] = g[idx];
    else            gb[idx] = bb[idx - 1024];
}

__global__ void wo2t_kernel(const float* __restrict__ W_o2, float* __restrict__ Wo2t)
{
    int idx = blockIdx.x * 256 + threadIdx.x; // 256 blocks -> 65536
    int k = idx >> 6, n = idx & 63;
    Wo2t[idx] = W_o2[n * 1024 + k];
}

// split a matrix [N x K] (src row stride src_ld, col offset col0) into hi/lo
__global__ void wsplit_kernel(const float* __restrict__ src, int src_ld, int col0,
                              int N, int K, unsigned short* __restrict__ hi,
                              unsigned short* __restrict__ lo)
{
    int idx = blockIdx.x * 256 + threadIdx.x;
    if (idx >= N * K) return;
    int n = idx / K, k = idx - n * K;
    float v = src[(size_t)n * src_ld + col0 + k];
    unsigned short h, l;
    split2(v, h, l);
    hi[idx] = h; lo[idx] = l;
}

// generic small fp32 GEMM (M may be < 64); act: 0 none, 1 tanh
__global__ void gemm64_kernel(const float* __restrict__ A, int lda, int M,
                              const float* __restrict__ W, int ldw, int K,
                              const float* __restrict__ bias,
                              float* __restrict__ C, int ldc, int act)
{
    __shared__ __align__(16) float At[16 * TS];
    __shared__ __align__(16) float Wt[16 * TS];
    float acc[4][4] = {};
    int b0 = blockIdx.x * 64, n0 = blockIdx.y * 64;
    gemm_tile64(A, lda, M, b0, W, ldw, n0, K, At, Wt, acc);
    int tx = threadIdx.x & 15, ty = threadIdx.x >> 4;
#pragma unroll
    for (int i = 0; i < 4; ++i) {
        int b = b0 + ty * 4 + i;
        if (b >= M) continue;
#pragma unroll
        for (int j = 0; j < 4; ++j) {
            int n = n0 + tx * 4 + j;
            float v = acc[i][j] + (bias ? bias[n] : 0.f);
            if (act == 1) v = tanhf(v);
            C[(size_t)b * ldc + n] = v;
        }
    }
}

// x0 = relu(cin0 + bpart[prev]) -> split
__global__ void xbuild0s_kernel(const float* __restrict__ cin0, const float* __restrict__ bpart,
                                const int* __restrict__ prev,
                                unsigned short* __restrict__ xh, unsigned short* __restrict__ xl)
{
    int b = blockIdx.x, tid = threadIdx.x;
    int pb = prev[b];
#pragma unroll
    for (int jj = 0; jj < 4; ++jj) {
        int j = jj * 256 + tid;
        float v = fmaxf(cin0[(size_t)b * 1024 + j] + bpart[(size_t)pb * 1024 + j], 0.f);
        unsigned short h, l;
        split2(v, h, l);
        xh[(size_t)b * 1024 + j] = h;
        xl[(size_t)b * 1024 + j] = l;
    }
}

// fp32 xbuild (fallback)
__global__ void xbuild0_kernel(const float* __restrict__ cin0, const float* __restrict__ bpart,
                               const int* __restrict__ prev, float* __restrict__ x)
{
    int b = blockIdx.x, tid = threadIdx.x;
    int pb = prev[b];
#pragma unroll
    for (int jj = 0; jj < 4; ++jj) {
        int j = jj * 256 + tid;
        x[(size_t)b * 1024 + j] = fmaxf(cin0[(size_t)b * 1024 + j] + bpart[(size_t)pb * 1024 + j], 0.f);
    }
}

// -------------------- per-step MFMA kernels (round 4) ----------------------

// Fused 8-way GEMM: grid (32, 8): x = tile (tm 0..3, tn 0..7), y = z.
// z 0..5: gate GEMMs (g=z%3, s=z/3); z=6: cin[t+1]; z=7: octx[t].
// Block: 512 threads = 8 waves (wr 0..3, wc 0..1); tile 64(M) x 128(N).
__global__ __launch_bounds__(512, 2) void gates_kernel(
    const unsigned short* __restrict__ xh, const unsigned short* __restrict__ xl,
    const unsigned short* __restrict__ hh, const unsigned short* __restrict__ hl,
    const unsigned short* __restrict__ ctxh, const unsigned short* __restrict__ ctxl,
    const unsigned short* __restrict__ wih_hi, const unsigned short* __restrict__ wih_lo,
    const unsigned short* __restrict__ whh_hi, const unsigned short* __restrict__ whh_lo,
    const unsigned short* __restrict__ wcin_hi, const unsigned short* __restrict__ wcin_lo,
    const unsigned short* __restrict__ wo1c_hi, const unsigned short* __restrict__ wo1c_lo,
    const float* __restrict__ b_in, const float* __restrict__ b_o1,
    float* __restrict__ g6, float* __restrict__ cin, float* __restrict__ octx,
    int t)
{
    const int z = blockIdx.y;
    if (z == 6 && t + 1 >= TT) return;
    const int tile = blockIdx.x;
    const int tm = tile & 3, tn = tile >> 2;
    const int tid = threadIdx.x, lane = tid & 63, wid = tid >> 6;
    const int wr = wid >> 1, wc = wid & 1;
    const int b0 = tm * 64, n0 = tn * 128;

    const unsigned short *Ah, *Al, *Bh, *Bl;
    int lda, K;
    const float* bias = nullptr;
    float* C;
    if (z < 6) {
        int g = z % 3, s = z / 3;
        Ah = s ? hh : xh; Al = s ? hl : xl; lda = 1024; K = 1024;
        Bh = (s ? whh_hi : wih_hi) + (size_t)g * 1048576;
        Bl = (s ? whh_lo : wih_lo) + (size_t)g * 1048576;
        C = g6 + (size_t)z * SZ;
    } else if (z == 6) {
        int s = (t + 1) & 1;
        Ah = ctxh + (size_t)s * 131072; Al = ctxl + (size_t)s * 131072;
        lda = 512; K = 512;
        Bh = wcin_hi; Bl = wcin_lo; bias = b_in; C = cin;
    } else {
        int s = t & 1;
        Ah = ctxh + (size_t)s * 131072; Al = ctxl + (size_t)s * 131072;
        lda = 512; K = 512;
        Bh = wo1c_hi; Bl = wo1c_lo; bias = b_o1; C = octx;
    }

    f32x4 acc[4] = {};
    wave_gemm_16x64(Ah, Al, lda, b0 + wr * 16, Bh, Bl, K, n0 + wc * 64, lane, acc);

    const int l15 = lane & 15, g4 = (lane >> 4) * 4;
#pragma unroll
    for (int ni = 0; ni < 4; ++ni) {
        int col = n0 + wc * 64 + ni * 16 + l15;
        float bv = bias ? bias[col] : 0.f;
#pragma unroll
        for (int r = 0; r < 4; ++r) {
            int row = b0 + wr * 16 + g4 + r;
            C[(size_t)row * 1024 + col] = acc[ni][r] + bv;
        }
    }
}

// o-GEMM with folded LN epilogue: grid (8, 8), 256 thr (4 waves), tile 32x128
__global__ __launch_bounds__(256, 2) void kb2_kernel(
    const unsigned short* __restrict__ hgh, const unsigned short* __restrict__ hgl,
    const unsigned short* __restrict__ w_hi, const unsigned short* __restrict__ w_lo,
    const float* __restrict__ uv, const float* __restrict__ octx,
    const float* __restrict__ mbuf, const float* __restrict__ isbuf,
    float* __restrict__ o)
{
    const int b0 = blockIdx.x * 32, n0 = blockIdx.y * 128;
    const int tid = threadIdx.x, lane = tid & 63, wid = tid >> 6;
    const int wr = wid >> 1, wc = wid & 1;

    f32x4 acc[4] = {};
    wave_gemm_16x64(hgh, hgl, 1024, b0 + wr * 16, w_hi, w_lo, 1024, n0 + wc * 64, lane, acc);

    const int l15 = lane & 15, g4 = (lane >> 4) * 4;
#pragma unroll
    for (int ni = 0; ni < 4; ++ni) {
        int col = n0 + wc * 64 + ni * 16 + l15;
        float u = uv[col], vb = uv[1024 + col];
#pragma unroll
        for (int r = 0; r < 4; ++r) {
            int row = b0 + wr * 16 + g4 + r;
            float m = mbuf[row], is = isbuf[row];
            float v = (acc[ni][r] - m * u) * is + vb + octx[(size_t)row * 1024 + col];
            o[(size_t)row * 1024 + col] = fmaxf(v, 0.f);
        }
    }
}

// GRU combine + LN stats; writes h fp32 in-place + split h + split hg
__global__ void gru_ln2_kernel(const float* __restrict__ g6,
                               const float* __restrict__ b_ih, const float* __restrict__ b_hh,
                               float* __restrict__ h, const float* __restrict__ ln_g,
                               unsigned short* __restrict__ hh, unsigned short* __restrict__ hl,
                               unsigned short* __restrict__ hgh, unsigned short* __restrict__ hgl,
                               float* __restrict__ mbuf, float* __restrict__ isbuf)
{
    __shared__ float ls[4], lq[4];
    int b = blockIdx.x, tid = threadIdx.x;
    float s = 0.f, q = 0.f;
#pragma unroll
    for (int jj = 0; jj < 4; ++jj) {
        int j = jj * 256 + tid;
        size_t base = (size_t)b * 1024 + j;
        float xr = g6[0 * (size_t)SZ + base] + b_ih[j];
        float xz = g6[1 * (size_t)SZ + base] + b_ih[1024 + j];
        float xn = g6[2 * (size_t)SZ + base] + b_ih[2048 + j];
        float hr = g6[3 * (size_t)SZ + base] + b_hh[j];
        float hz = g6[4 * (size_t)SZ + base] + b_hh[1024 + j];
        float hn = g6[5 * (size_t)SZ + base] + b_hh[2048 + j];
        float r = 1.f / (1.f + expf(-(xr + hr)));
        float z = 1.f / (1.f + expf(-(xz + hz)));
        float nn = tanhf(xn + r * hn);
        float ho = h[base];
        float hv = (1.f - z) * nn + z * ho;
        h[base] = hv;
        unsigned short a, c;
        split2(hv, a, c); hh[base] = a; hl[base] = c;
        float hgv = hv * ln_g[j];
        split2(hgv, a, c); hgh[base] = a; hgl[base] = c;
        s += hv; q += hv * hv;
    }
    for (int off = 32; off; off >>= 1) {
        s += __shfl_down(s, off);
        q += __shfl_down(q, off);
    }
    int lane = tid & 63, w = tid >> 6;
    if (lane == 0) { ls[w] = s; lq[w] = q; }
    __syncthreads();
    if (tid == 0) {
        float S = ls[0] + ls[1] + ls[2] + ls[3];
        float Q = lq[0] + lq[1] + lq[2] + lq[3];
        float m = S * (1.f / 1024.f);
        mbuf[b] = m;
        isbuf[b] = rsqrtf(Q * (1.f / 1024.f) - m * m + 1e-5f);
    }
}

// logits + argmax + next-x build + ctx split; 64 blocks x 256 thr, 4 rows each
__global__ void kc2_kernel(const float* __restrict__ o, const float* __restrict__ Wo2t,
                           const float* __restrict__ b_o2, const float* __restrict__ cin,
                           const float* __restrict__ bpart, const float* __restrict__ ctx,
                           unsigned short* __restrict__ xh, unsigned short* __restrict__ xl,
                           unsigned short* __restrict__ ctxh, unsigned short* __restrict__ ctxl,
                           int* __restrict__ prev, float* __restrict__ out, int t)
{
    __shared__ __align__(16) float os[4][1024];
    __shared__ float red[4][4][64];
    __shared__ int sidx[4];
    const int b0 = blockIdx.x * 4, tid = threadIdx.x;

#pragma unroll
    for (int i = 0; i < 4; ++i) {
        int f = tid + i * 256;             // float4 index, 0..1023
        int r = f >> 8, c4 = (f & 255) << 2;
        *(float4*)&os[r][c4] = *(const float4*)(o + (size_t)(b0 + r) * 1024 + c4);
    }
    __syncthreads();

    {
        int n = tid & 63, seg = tid >> 6;
        float p0 = 0.f, p1 = 0.f, p2 = 0.f, p3 = 0.f;
        int k0 = seg * 256;
        for (int k = k0; k < k0 + 256; ++k) {
            float w = Wo2t[(size_t)k * 64 + n];
            p0 += os[0][k] * w; p1 += os[1][k] * w;
            p2 += os[2][k] * w; p3 += os[3][k] * w;
        }
        red[0][seg][n] = p0; red[1][seg][n] = p1;
        red[2][seg][n] = p2; red[3][seg][n] = p3;
    }
    __syncthreads();

    {
        int r = tid >> 6, n = tid & 63;
        float lg = red[r][0][n] + red[r][1][n] + red[r][2][n] + red[r][3][n] + b_o2[n];
        out[(size_t)(b0 + r) * (TT * 64) + t * 64 + n] = lg;
        float v = lg; int idx = n;
        for (int off = 32; off; off >>= 1) {
            float ov = __shfl_xor(v, off);
            int oi = __shfl_xor(idx, off);
            if (ov > v || (ov == v && oi < idx)) { v = ov; idx = oi; }
        }
        if (n == 0) { prev[b0 + r] = idx; sidx[r] = idx; }
    }
    __syncthreads();

    if (t + 1 < TT) {
#pragma unroll
        for (int i = 0; i < 16; ++i) {
            int idx = tid + i * 256;       // 0..4095
            int r = idx >> 10, j = idx & 1023;
            float v = fmaxf(cin[(size_t)(b0 + r) * 1024 + j] +
                            bpart[(size_t)sidx[r] * 1024 + j], 0.f);
            unsigned short h, l;
            split2(v, h, l);
            xh[(size_t)(b0 + r) * 1024 + j] = h;
            xl[(size_t)(b0 + r) * 1024 + j] = l;
        }
    }
    if (t + 2 < TT) {
        int slot = t & 1;
#pragma unroll
        for (int i = 0; i < 8; ++i) {
            int idx = tid + i * 256;       // 0..2047
            int r = idx >> 9, j = idx & 511;
            float v = ctx[(size_t)(b0 + r) * LDA_CTX + (t + 2) * 512 + j];
            unsigned short h, l;
            split2(v, h, l);
            ctxh[(size_t)slot * 131072 + (size_t)(b0 + r) * 512 + j] = h;
            ctxl[(size_t)slot * 131072 + (size_t)(b0 + r) * 512 + j] = l;
        }
    }
}

// -------------------- fallback fp32 step kernels (round 1) -----------------

__global__ void step_gemms_kernel(
    const float* __restrict__ x, const float* __restrict__ hBase,
    const float* __restrict__ ctx,
    const float* __restrict__ Wih, const float* __restrict__ Whh,
    const float* __restrict__ Win, const float* __restrict__ Wo1,
    const float* __restrict__ b_in, const float* __restrict__ b_o1,
    float* __restrict__ g6, float* __restrict__ cinBase, float* __restrict__ octx,
    int t)
{
    __shared__ __align__(16) float At[16 * TS];
    __shared__ __align__(16) float Wt[16 * TS];
    float acc[4][4] = {};
    const int z = blockIdx.z, b0 = blockIdx.x * 64, n0 = blockIdx.y * 64;
    const float *A, *W, *bias = nullptr;
    float* C;
    int lda, ldw, K;
    if (z < 6) {
        int g = z % 3, s = z / 3;
        A = s ? (hBase + (size_t)(t & 1) * SZ) : x;
        lda = 1024;
        W = (s ? Whh : Wih) + (size_t)(g * 1024) * 1024;
        ldw = 1024; K = 1024;
        C = g6 + (size_t)z * SZ;
    } else if (z == 6) {
        if (t + 1 >= TT) return;
        A = ctx + (size_t)(t + 1) * 512; lda = LDA_CTX;
        W = Win; ldw = 1024; K = 512; bias = b_in;
        C = cinBase + (size_t)((t + 1) & 1) * SZ;
    } else {
        A = ctx + (size_t)t * 512; lda = LDA_CTX;
        W = Wo1 + 1024; ldw = 1536; K = 512; bias = b_o1;
        C = octx;
    }
    gemm_tile64(A, lda, 256, b0, W, ldw, n0, K, At, Wt, acc);
    int tx = threadIdx.x & 15, ty = threadIdx.x >> 4;
#pragma unroll
    for (int i = 0; i < 4; ++i) {
        int b = b0 + ty * 4 + i;
#pragma unroll
        for (int j = 0; j < 4; ++j) {
            int n = n0 + tx * 4 + j;
            float v = acc[i][j];
            if (bias) v += bias[n];
            C[(size_t)b * 1024 + n] = v;
        }
    }
}

__global__ void kb_kernel(const float* __restrict__ hg, const float* __restrict__ Wo1,
                          const float* __restrict__ uv, const float* __restrict__ octx,
                          const float* __restrict__ mbuf, const float* __restrict__ isbuf,
                          float* __restrict__ o)
{
    __shared__ __align__(16) float At[16 * TS];
    __shared__ __align__(16) float Wt[16 * TS];
    float acc[2][4] = {};
    const int b0 = blockIdx.x * 32, n0 = blockIdx.y * 64;
    const int tid = threadIdx.x, tx = tid & 15, ty = tid >> 4;
    const int r = tid >> 2, c0 = (tid & 3) << 2;
    for (int k0 = 0; k0 < 1024; k0 += 16) {
        float4 av = make_float4(0.f, 0.f, 0.f, 0.f);
        if (r < 32) av = *(const float4*)(hg + (size_t)(b0 + r) * 1024 + k0 + c0);
        float4 wv = *(const float4*)(Wo1 + (size_t)(n0 + r) * 1536 + k0 + c0);
        __syncthreads();
        At[(c0+0)*TS + r] = av.x; At[(c0+1)*TS + r] = av.y;
        At[(c0+2)*TS + r] = av.z; At[(c0+3)*TS + r] = av.w;
        Wt[(c0+0)*TS + r] = wv.x; Wt[(c0+1)*TS + r] = wv.y;
        Wt[(c0+2)*TS + r] = wv.z; Wt[(c0+3)*TS + r] = wv.w;
        __syncthreads();
#pragma unroll
        for (int kk = 0; kk < 16; ++kk) {
            float2 a = *(const float2*)(At + kk*TS + ty*2);
            float4 w = *(const float4*)(Wt + kk*TS + tx*4);
            acc[0][0] += a.x*w.x; acc[0][1] += a.x*w.y; acc[0][2] += a.x*w.z; acc[0][3] += a.x*w.w;
            acc[1][0] += a.y*w.x; acc[1][1] += a.y*w.y; acc[1][2] += a.y*w.z; acc[1][3] += a.y*w.w;
        }
    }
#pragma unroll
    for (int i = 0; i < 2; ++i) {
        int b = b0 + ty * 2 + i;
        float m = mbuf[b], is = isbuf[b];
#pragma unroll
        for (int j = 0; j < 4; ++j) {
            int n = n0 + tx * 4 + j;
            float v = (acc[i][j] - m * uv[n]) * is + uv[1024 + n] + octx[(size_t)b * 1024 + n];
            o[(size_t)b * 1024 + n] = fmaxf(v, 0.f);
        }
    }
}

__global__ void gru_ln_kernel(const float* __restrict__ g6,
                              const float* __restrict__ b_ih, const float* __restrict__ b_hh,
                              float* __restrict__ hBase, const float* __restrict__ ln_g,
                              float* __restrict__ hg, float* __restrict__ mbuf,
                              float* __restrict__ isbuf, int t)
{
    __shared__ float rs[256], rq[256];
    int b = blockIdx.x, tid = threadIdx.x;
    const float* hc = hBase + (size_t)(t & 1) * SZ + (size_t)b * 1024;
    float* hnx = hBase + (size_t)((t + 1) & 1) * SZ + (size_t)b * 1024;
    float s = 0.f, q = 0.f;
#pragma unroll
    for (int jj = 0; jj < 4; ++jj) {
        int j = jj * 256 + tid;
        size_t base = (size_t)b * 1024 + j;
        float xr = g6[0 * (size_t)SZ + base] + b_ih[j];
        float xz = g6[1 * (size_t)SZ + base] + b_ih[1024 + j];
        float xn = g6[2 * (size_t)SZ + base] + b_ih[2048 + j];
        float hr = g6[3 * (size_t)SZ + base] + b_hh[j];
        float hz = g6[4 * (size_t)SZ + base] + b_hh[1024 + j];
        float hn = g6[5 * (size_t)SZ + base] + b_hh[2048 + j];
        float r = 1.f / (1.f + expf(-(xr + hr)));
        float z = 1.f / (1.f + expf(-(xz + hz)));
        float nn = tanhf(xn + r * hn);
        float ho = hc[j];
        float hv = (1.f - z) * nn + z * ho;
        hnx[j] = hv;
        hg[base] = hv * ln_g[j];
        s += hv; q += hv * hv;
    }
    rs[tid] = s; rq[tid] = q;
    __syncthreads();
    for (int st = 128; st; st >>= 1) {
        if (tid < st) { rs[tid] += rs[tid + st]; rq[tid] += rq[tid + st]; }
        __syncthreads();
    }
    if (tid == 0) {
        float m = rs[0] * (1.f / 1024.f);
        float var = rq[0] * (1.f / 1024.f) - m * m;
        mbuf[b] = m;
        isbuf[b] = rsqrtf(var + 1e-5f);
    }
}

__global__ void kc_kernel(const float* __restrict__ o, const float* __restrict__ Wo2t,
                          const float* __restrict__ b_o2, const float* __restrict__ cinBase,
                          const float* __restrict__ bpart, float* __restrict__ x,
                          int* __restrict__ prev, float* __restrict__ out, int t)
{
    __shared__ __align__(16) float os[1024];
    __shared__ float red[4][64];
    __shared__ int sidx;
    int b = blockIdx.x, tid = threadIdx.x;
    const float* orow = o + (size_t)b * 1024;
    *(float4*)&os[tid * 4] = *(const float4*)&orow[tid * 4];
    __syncthreads();
    int n = tid & 63, seg = tid >> 6;
    float p = 0.f;
    int k0 = seg * 256;
#pragma unroll 8
    for (int k = 0; k < 256; ++k) p += os[k0 + k] * Wo2t[(size_t)(k0 + k) * 64 + n];
    red[seg][n] = p;
    __syncthreads();
    if (tid < 64) {
        float lg = red[0][tid] + red[1][tid] + red[2][tid] + red[3][tid] + b_o2[tid];
        out[((size_t)b * TT + t) * 64 + tid] = lg;
        float v = lg; int idx = tid;
        for (int off = 32; off; off >>= 1) {
            float ov = __shfl_xor(v, off);
            int oi = __shfl_xor(idx, off);
            if (ov > v || (ov == v && oi < idx)) { v = ov; idx = oi; }
        }
        if (tid == 0) { prev[b] = idx; sidx = idx; }
    }
    __syncthreads();
    if (t + 1 < TT) {
        int pb = sidx;
        const float* cn = cinBase + (size_t)((t + 1) & 1) * SZ + (size_t)b * 1024;
        const float* bp = bpart + (size_t)pb * 1024;
#pragma unroll
        for (int jj = 0; jj < 4; ++jj) {
            int j = jj * 256 + tid;
            x[(size_t)b * 1024 + j] = fmaxf(cn[j] + bp[j], 0.f);
        }
    }
}

// ---------------------------------------------------------------------------

extern "C" void kernel_launch(void* const* d_in, const int* in_sizes, int n_in,
                              void* d_out, int out_size, void* d_ws, size_t ws_size,
                              hipStream_t stream)
{
    const float* ctx    = (const float*)d_in[0];
    const int*   bh     = (const int*)d_in[1];
    const float* be     = (const float*)d_in[2];
    const float* W_in   = (const float*)d_in[3];
    const float* b_in   = (const float*)d_in[4];
    const float* W_init = (const float*)d_in[5];
    const float* b_init = (const float*)d_in[6];
    const float* W_ih   = (const float*)d_in[7];
    const float* b_ih   = (const float*)d_in[8];
    const float* W_hh   = (const float*)d_in[9];
    const float* b_hh   = (const float*)d_in[10];
    const float* ln_g   = (const float*)d_in[11];
    const float* ln_b   = (const float*)d_in[12];
    const float* W_o1   = (const float*)d_in[13];
    const float* b_o1   = (const float*)d_in[14];
    const float* W_o2   = (const float*)d_in[15];
    const float* b_o2   = (const float*)d_in[16];
    float* out = (float*)d_out;
    float* ws  = (float*)d_ws;

    const bool mfma_path = (ws_size >= 49830000ull);

    if (mfma_path) {
        // ---- round-4 layout ----
        float* A0    = ws;                 // setup only; aliases obuf
        float* obuf  = ws;
        float* hbuf  = ws + 262144;        // h fp32 (in-place)
        float* cin   = ws + 524288;
        float* octx  = ws + 786432;
        float* g6    = ws + 1048576;       // 6 slots
        float* bpart = ws + 2621440;       // 64x1024
        float* uvv   = ws + 2686976;       // 2x1024
        float* gb    = ws + 2689024;       // 2x1024
        float* Wo2t  = ws + 2691072;       // 1024x64
        float* mbuf  = ws + 2756608;
        float* isbuf = ws + 2756864;
        int*   prev  = (int*)(ws + 2757120);
        unsigned short* bf = (unsigned short*)(ws + 2757632);
        unsigned short* wih_hi  = bf;
        unsigned short* wih_lo  = bf + 3145728;
        unsigned short* whh_hi  = bf + 6291456;
        unsigned short* whh_lo  = bf + 9437184;
        unsigned short* wo1k_hi = bf + 12582912;
        unsigned short* wo1k_lo = bf + 13631488;
        unsigned short* wo1c_hi = bf + 14680064;
        unsigned short* wo1c_lo = bf + 15204352;
        unsigned short* wcin_hi = bf + 15728640;
        unsigned short* wcin_lo = bf + 16252928;
        unsigned short* xh   = bf + 16777216;
        unsigned short* xl   = bf + 17039360;
        unsigned short* hh   = bf + 17301504;
        unsigned short* hl   = bf + 17563648;
        unsigned short* hgh  = bf + 17825792;
        unsigned short* hgl  = bf + 18087936;
        unsigned short* ctxh = bf + 18350080;   // [2][256][512]
        unsigned short* ctxl = bf + 18612224;

        // ---- setup ----
        pre0_kernel<<<256, 512, 0, stream>>>(ctx, bh, be, A0, prev);
        copy_gb_kernel<<<8, 256, 0, stream>>>(ln_g, ln_b, gb);
        wo2t_kernel<<<256, 256, 0, stream>>>(W_o2, Wo2t);
        gemm64_kernel<<<dim3(4, 16), 256, 0, stream>>>(A0, 1024, 256, W_init, 1024, 1024,
                                                       b_init, hbuf, 1024, 1);
        gemm64_kernel<<<dim3(1, 16), 256, 0, stream>>>(be, 512, 64, W_in + 512, 1024, 512,
                                                       nullptr, bpart, 1024, 0);
        gemm64_kernel<<<dim3(1, 16), 256, 0, stream>>>(gb, 1024, 2, W_o1, 1536, 1024,
                                                       nullptr, uvv, 1024, 0);
        gemm64_kernel<<<dim3(4, 16), 256, 0, stream>>>(ctx, LDA_CTX, 256, W_in, 1024, 512,
                                                       b_in, cin, 1024, 0);
        xbuild0s_kernel<<<256, 256, 0, stream>>>(cin, bpart, prev, xh, xl);
        // weight splits
        wsplit_kernel<<<12288, 256, 0, stream>>>(W_ih, 1024, 0, 3072, 1024, wih_hi, wih_lo);
        wsplit_kernel<<<12288, 256, 0, stream>>>(W_hh, 1024, 0, 3072, 1024, whh_hi, whh_lo);
        wsplit_kernel<<<4096, 256, 0, stream>>>(W_o1, 1536, 0, 1024, 1024, wo1k_hi, wo1k_lo);
        wsplit_kernel<<<2048, 256, 0, stream>>>(W_o1, 1536, 1024, 1024, 512, wo1c_hi, wo1c_lo);
        wsplit_kernel<<<2048, 256, 0, stream>>>(W_in, 1024, 0, 1024, 512, wcin_hi, wcin_lo);
        // activation splits: h0, ctx slices 0 and 1
        wsplit_kernel<<<1024, 256, 0, stream>>>(hbuf, 1024, 0, 256, 1024, hh, hl);
        wsplit_kernel<<<512, 256, 0, stream>>>(ctx, LDA_CTX, 0, 256, 512,
                                               ctxh, ctxl);
        wsplit_kernel<<<512, 256, 0, stream>>>(ctx, LDA_CTX, 512, 256, 512,
                                               ctxh + 131072, ctxl + 131072);

        // ---- recurrence ----
        for (int t = 0; t < TT; ++t) {
            gates_kernel<<<dim3(32, 8), 512, 0, stream>>>(
                xh, xl, hh, hl, ctxh, ctxl,
                wih_hi, wih_lo, whh_hi, whh_lo, wcin_hi, wcin_lo, wo1c_hi, wo1c_lo,
                b_in, b_o1, g6, cin, octx, t);
            gru_ln2_kernel<<<256, 256, 0, stream>>>(g6, b_ih, b_hh, hbuf, ln_g,
                                                    hh, hl, hgh, hgl, mbuf, isbuf);
            kb2_kernel<<<dim3(8, 8), 256, 0, stream>>>(hgh, hgl, wo1k_hi, wo1k_lo,
                                                       uvv, octx, mbuf, isbuf, obuf);
            kc2_kernel<<<64, 256, 0, stream>>>(obuf, Wo2t, b_o2, cin, bpart, ctx,
                                               xh, xl, ctxh, ctxl, prev, out, t);
        }
    } else {
        // ---- fallback: round-1 fp32 path, old layout ----
        float* A0    = ws;
        float* hbuf  = ws + 262144;
        float* hg    = ws + 786432;
        float* x     = ws + 1048576;
        float* cin   = ws + 1310720;
        float* octx  = ws + 1835008;
        float* g6    = ws + 2097152;
        float* obuf  = ws + 3670016;
        float* bpart = ws + 3932160;
        float* uvv   = ws + 3997696;
        float* gb    = ws + 3999744;
        float* Wo2t  = ws + 4001792;
        float* mbuf  = ws + 4067328;
        float* isbuf = ws + 4067584;
        int*   prev  = (int*)(ws + 4067840);

        pre0_kernel<<<256, 512, 0, stream>>>(ctx, bh, be, A0, prev);
        copy_gb_kernel<<<8, 256, 0, stream>>>(ln_g, ln_b, gb);
        wo2t_kernel<<<256, 256, 0, stream>>>(W_o2, Wo2t);
        gemm64_kernel<<<dim3(4, 16), 256, 0, stream>>>(A0, 1024, 256, W_init, 1024, 1024,
                                                       b_init, hbuf, 1024, 1);
        gemm64_kernel<<<dim3(1, 16), 256, 0, stream>>>(be, 512, 64, W_in + 512, 1024, 512,
                                                       nullptr, bpart, 1024, 0);
        gemm64_kernel<<<dim3(1, 16), 256, 0, stream>>>(gb, 1024, 2, W_o1, 1536, 1024,
                                                       nullptr, uvv, 1024, 0);
        gemm64_kernel<<<dim3(4, 16), 256, 0, stream>>>(ctx, LDA_CTX, 256, W_in, 1024, 512,
                                                       b_in, cin, 1024, 0);
        xbuild0_kernel<<<256, 256, 0, stream>>>(cin, bpart, prev, x);

        for (int t = 0; t < TT; ++t) {
            step_gemms_kernel<<<dim3(4, 16, 8), 256, 0, stream>>>(
                x, hbuf, ctx, W_ih, W_hh, W_in, W_o1, b_in, b_o1, g6, cin, octx, t);
            gru_ln_kernel<<<256, 256, 0, stream>>>(g6, b_ih, b_hh, hbuf, ln_g, hg,
                                                   mbuf, isbuf, t);
            kb_kernel<<<dim3(8, 16), 256, 0, stream>>>(hg, W_o1, uvv, octx, mbuf, isbuf, obuf);
            kc_kernel<<<256, 256, 0, stream>>>(obuf, Wo2t, b_o2, cin, bpart, x, prev, out, t);
        }
    }
}

// Round 5
// 8685.725 us; speedup vs baseline: 2.0196x; 2.0196x over previous
//
#include <hip/hip_runtime.h>
#include <hip/hip_bf16.h>

// ---------------------------------------------------------------------------
// AutoregressiveBeamDecoder: B=256, T=128, D=512, H=1024, NB=64, HH=8
// Round 5: LDS-staged split-bf16 MFMA GEMMs (round-3 structure) +
//   - pre-split activations from producers (round-4 idea, kept)
//   - BK=64 (half the barriers), LDS stride 72 (conflict-neutral b128 reads)
//   - 512-thread blocks (2 waves/SIMD)
//   - XCD-aware 1-D block id: id = z*32 + tm*8 + tn  (tn-class -> one XCD's L2)
// C = Ahi@Whi + Ahi@Wlo + Alo@Whi  (3x mfma_f32_16x16x32_bf16, fp32 accum)
// ---------------------------------------------------------------------------

#define TS 68          // fp32 LDS row stride (fallback path only)
constexpr int SZ = 262144;     // 256*1024
constexpr int TT = 128;        // T
constexpr int LDA_CTX = 65536; // T*D

typedef __attribute__((ext_vector_type(8))) short short8_t;
typedef __attribute__((ext_vector_type(4))) float f32x4;

// ---------------- bf16 split helpers (bit-level, RNE) ----------------------

__device__ __forceinline__ unsigned short f2bf_rne(float v) {
    unsigned u = __float_as_uint(v);
    unsigned r = u + 0x7fffu + ((u >> 16) & 1u);
    return (unsigned short)(r >> 16);
}
__device__ __forceinline__ float bfbits2f(unsigned short h) {
    return __uint_as_float(((unsigned)h) << 16);
}
__device__ __forceinline__ void split2(float v, unsigned short& h, unsigned short& l) {
    h = f2bf_rne(v);
    l = f2bf_rne(v - bfbits2f(h));
}

// ---------------- 64x128-tile LDS-staged split-bf16 GEMM core --------------
// 512 threads = 8 waves; wave (wr 0..3, wc 0..1) owns 16x64 (1 A-frag, 4 B).
// BK=64; LDS row stride 72 shorts (144 B). K multiple of 64.
// sm layout (shorts): As_h[64*72] As_l[64*72] Bs_h[128*72] Bs_l[128*72]

__device__ __forceinline__ void mfma_tile_64x128(
    const unsigned short* __restrict__ Ah, const unsigned short* __restrict__ Al,
    int lda, int b0,
    const unsigned short* __restrict__ Bh, const unsigned short* __restrict__ Bl,
    int K, int n0, unsigned short* sm, f32x4 acc[4])
{
    const int tid = threadIdx.x, lane = tid & 63, wid = tid >> 6;
    const int wr = wid >> 1, wc = wid & 1;
    const int l15 = lane & 15, kg = (lane >> 4) * 8;
    const int ar = tid >> 3, ac = (tid & 7) * 8;   // A stage: 8 thr/row
    const int br = tid >> 2, bc = (tid & 3) * 16;  // B stage: 4 thr/row, 16 shorts
    unsigned short* As_h = sm;
    unsigned short* As_l = sm + 4608;
    unsigned short* Bs_h = sm + 9216;
    unsigned short* Bs_l = sm + 18432;
    const unsigned short* gAh = Ah + (size_t)(b0 + ar) * lda + ac;
    const unsigned short* gAl = Al + (size_t)(b0 + ar) * lda + ac;
    const unsigned short* gBh = Bh + (size_t)(n0 + br) * K + bc;
    const unsigned short* gBl = Bl + (size_t)(n0 + br) * K + bc;

    for (int k0 = 0; k0 < K; k0 += 64) {
        short8_t vah  = *(const short8_t*)(gAh + k0);
        short8_t val_ = *(const short8_t*)(gAl + k0);
        short8_t vbh0 = *(const short8_t*)(gBh + k0);
        short8_t vbh1 = *(const short8_t*)(gBh + k0 + 8);
        short8_t vbl0 = *(const short8_t*)(gBl + k0);
        short8_t vbl1 = *(const short8_t*)(gBl + k0 + 8);
        __syncthreads();
        *(short8_t*)&As_h[ar * 72 + ac] = vah;
        *(short8_t*)&As_l[ar * 72 + ac] = val_;
        *(short8_t*)&Bs_h[br * 72 + bc]     = vbh0;
        *(short8_t*)&Bs_h[br * 72 + bc + 8] = vbh1;
        *(short8_t*)&Bs_l[br * 72 + bc]     = vbl0;
        *(short8_t*)&Bs_l[br * 72 + bc + 8] = vbl1;
        __syncthreads();
#pragma unroll
        for (int ks = 0; ks < 2; ++ks) {
            const int ko = ks * 32 + kg;
            short8_t a_h = *(const short8_t*)&As_h[(wr * 16 + l15) * 72 + ko];
            short8_t a_l = *(const short8_t*)&As_l[(wr * 16 + l15) * 72 + ko];
#pragma unroll
            for (int ni = 0; ni < 4; ++ni) {
                const int boff = (wc * 64 + ni * 16 + l15) * 72 + ko;
                short8_t b_h = *(const short8_t*)&Bs_h[boff];
                short8_t b_l = *(const short8_t*)&Bs_l[boff];
                acc[ni] = __builtin_amdgcn_mfma_f32_16x16x32_bf16(a_h, b_h, acc[ni], 0, 0, 0);
                acc[ni] = __builtin_amdgcn_mfma_f32_16x16x32_bf16(a_h, b_l, acc[ni], 0, 0, 0);
                acc[ni] = __builtin_amdgcn_mfma_f32_16x16x32_bf16(a_l, b_h, acc[ni], 0, 0, 0);
            }
        }
    }
}

// ---------------- fp32 tiled GEMM core (setup + fallback) ------------------

__device__ __forceinline__ void gemm_tile64(
    const float* __restrict__ A, int lda, int Mlim, int b0,
    const float* __restrict__ W, int ldw, int n0, int K,
    float* At, float* Wt, float acc[4][4])
{
    const int tid = threadIdx.x;
    const int tx = tid & 15, ty = tid >> 4;
    const int r = tid >> 2, c0 = (tid & 3) << 2;
    for (int k0 = 0; k0 < K; k0 += 16) {
        float4 av = make_float4(0.f, 0.f, 0.f, 0.f);
        if (b0 + r < Mlim)
            av = *(const float4*)(A + (size_t)(b0 + r) * lda + k0 + c0);
        float4 wv = *(const float4*)(W + (size_t)(n0 + r) * ldw + k0 + c0);
        __syncthreads();
        At[(c0+0)*TS + r] = av.x; At[(c0+1)*TS + r] = av.y;
        At[(c0+2)*TS + r] = av.z; At[(c0+3)*TS + r] = av.w;
        Wt[(c0+0)*TS + r] = wv.x; Wt[(c0+1)*TS + r] = wv.y;
        Wt[(c0+2)*TS + r] = wv.z; Wt[(c0+3)*TS + r] = wv.w;
        __syncthreads();
#pragma unroll
        for (int kk = 0; kk < 16; ++kk) {
            float4 a = *(const float4*)(At + kk*TS + ty*4);
            float4 w = *(const float4*)(Wt + kk*TS + tx*4);
            acc[0][0] += a.x*w.x; acc[0][1] += a.x*w.y; acc[0][2] += a.x*w.z; acc[0][3] += a.x*w.w;
            acc[1][0] += a.y*w.x; acc[1][1] += a.y*w.y; acc[1][2] += a.y*w.z; acc[1][3] += a.y*w.w;
            acc[2][0] += a.z*w.x; acc[2][1] += a.z*w.y; acc[2][2] += a.z*w.z; acc[2][3] += a.z*w.w;
            acc[3][0] += a.w*w.x; acc[3][1] += a.w*w.y; acc[3][2] += a.w*w.z; acc[3][3] += a.w*w.w;
        }
    }
}

// -------------------- setup kernels ----------------------------------------

__global__ void pre0_kernel(const float* __restrict__ ctx, const int* __restrict__ bh,
                            const float* __restrict__ be, float* __restrict__ A0,
                            int* __restrict__ prev)
{
    int b = blockIdx.x, tid = threadIdx.x; // blockDim 512
    float s = 0.f;
    for (int t = 0; t < TT; ++t) s += ctx[(size_t)b * LDA_CTX + t * 512 + tid];
    A0[b * 1024 + tid] = s * (1.f / 128.f);
    float s2 = 0.f;
    for (int i = 0; i < 8; ++i) s2 += be[bh[b * 8 + i] * 512 + tid];
    A0[b * 1024 + 512 + tid] = s2 * 0.125f;
    if (tid == 0) prev[b] = bh[b * 8 + 7];
}

__global__ void copy_gb_kernel(const float* g, const float* bb, float* gb)
{
    int idx = blockIdx.x * 256 + threadIdx.x; // 8 blocks
    if (idx < 1024) gb[idx] = g[idx];
    else            gb[idx] = bb[idx - 1024];
}

__global__ void wo2t_kernel(const float* __restrict__ W_o2, float* __restrict__ Wo2t)
{
    int idx = blockIdx.x * 256 + threadIdx.x; // 256 blocks -> 65536
    int k = idx >> 6, n = idx & 63;
    Wo2t[idx] = W_o2[n * 1024 + k];
}

// split a matrix [N x K] (src row stride src_ld, col offset col0) into hi/lo
__global__ void wsplit_kernel(const float* __restrict__ src, int src_ld, int col0,
                              int N, int K, unsigned short* __restrict__ hi,
                              unsigned short* __restrict__ lo)
{
    int idx = blockIdx.x * 256 + threadIdx.x;
    if (idx >= N * K) return;
    int n = idx / K, k = idx - n * K;
    float v = src[(size_t)n * src_ld + col0 + k];
    unsigned short h, l;
    split2(v, h, l);
    hi[idx] = h; lo[idx] = l;
}

// generic small fp32 GEMM (M may be < 64); act: 0 none, 1 tanh
__global__ void gemm64_kernel(const float* __restrict__ A, int lda, int M,
                              const float* __restrict__ W, int ldw, int K,
                              const float* __restrict__ bias,
                              float* __restrict__ C, int ldc, int act)
{
    __shared__ __align__(16) float At[16 * TS];
    __shared__ __align__(16) float Wt[16 * TS];
    float acc[4][4] = {};
    int b0 = blockIdx.x * 64, n0 = blockIdx.y * 64;
    gemm_tile64(A, lda, M, b0, W, ldw, n0, K, At, Wt, acc);
    int tx = threadIdx.x & 15, ty = threadIdx.x >> 4;
#pragma unroll
    for (int i = 0; i < 4; ++i) {
        int b = b0 + ty * 4 + i;
        if (b >= M) continue;
#pragma unroll
        for (int j = 0; j < 4; ++j) {
            int n = n0 + tx * 4 + j;
            float v = acc[i][j] + (bias ? bias[n] : 0.f);
            if (act == 1) v = tanhf(v);
            C[(size_t)b * ldc + n] = v;
        }
    }
}

// x0 = relu(cin0 + bpart[prev]) -> split
__global__ void xbuild0s_kernel(const float* __restrict__ cin0, const float* __restrict__ bpart,
                                const int* __restrict__ prev,
                                unsigned short* __restrict__ xh, unsigned short* __restrict__ xl)
{
    int b = blockIdx.x, tid = threadIdx.x;
    int pb = prev[b];
#pragma unroll
    for (int jj = 0; jj < 4; ++jj) {
        int j = jj * 256 + tid;
        float v = fmaxf(cin0[(size_t)b * 1024 + j] + bpart[(size_t)pb * 1024 + j], 0.f);
        unsigned short h, l;
        split2(v, h, l);
        xh[(size_t)b * 1024 + j] = h;
        xl[(size_t)b * 1024 + j] = l;
    }
}

// fp32 xbuild (fallback)
__global__ void xbuild0_kernel(const float* __restrict__ cin0, const float* __restrict__ bpart,
                               const int* __restrict__ prev, float* __restrict__ x)
{
    int b = blockIdx.x, tid = threadIdx.x;
    int pb = prev[b];
#pragma unroll
    for (int jj = 0; jj < 4; ++jj) {
        int j = jj * 256 + tid;
        x[(size_t)b * 1024 + j] = fmaxf(cin0[(size_t)b * 1024 + j] + bpart[(size_t)pb * 1024 + j], 0.f);
    }
}

// -------------------- per-step MFMA kernels (round 5) ----------------------

// Fused 8-way GEMM; 1-D grid 256: bid = z*32 + tm*8 + tn (XCD class = tn).
// z 0..5: gate GEMMs (g=z%3, s=z/3); z=6: cin[t+1]; z=7: octx[t].
__global__ __launch_bounds__(512, 2) void gates5_kernel(
    const unsigned short* __restrict__ xh, const unsigned short* __restrict__ xl,
    const unsigned short* __restrict__ hh, const unsigned short* __restrict__ hl,
    const unsigned short* __restrict__ ctxh, const unsigned short* __restrict__ ctxl,
    const unsigned short* __restrict__ wih_hi, const unsigned short* __restrict__ wih_lo,
    const unsigned short* __restrict__ whh_hi, const unsigned short* __restrict__ whh_lo,
    const unsigned short* __restrict__ wcin_hi, const unsigned short* __restrict__ wcin_lo,
    const unsigned short* __restrict__ wo1c_hi, const unsigned short* __restrict__ wo1c_lo,
    const float* __restrict__ b_in, const float* __restrict__ b_o1,
    float* __restrict__ g6, float* __restrict__ cin, float* __restrict__ octx,
    int t)
{
    const int bid = blockIdx.x;
    const int z  = bid >> 5;
    const int tm = (bid >> 3) & 3;
    const int tn = bid & 7;
    if (z == 6 && t + 1 >= TT) return;
    const int b0 = tm * 64, n0 = tn * 128;

    const unsigned short *Ah, *Al, *Bh, *Bl;
    int lda, K;
    const float* bias = nullptr;
    float* C;
    if (z < 6) {
        int g = z % 3, s = z / 3;
        Ah = s ? hh : xh; Al = s ? hl : xl; lda = 1024; K = 1024;
        Bh = (s ? whh_hi : wih_hi) + (size_t)g * 1048576;
        Bl = (s ? whh_lo : wih_lo) + (size_t)g * 1048576;
        C = g6 + (size_t)z * SZ;
    } else if (z == 6) {
        int s = (t + 1) & 1;
        Ah = ctxh + (size_t)s * 131072; Al = ctxl + (size_t)s * 131072;
        lda = 512; K = 512;
        Bh = wcin_hi; Bl = wcin_lo; bias = b_in; C = cin;
    } else {
        int s = t & 1;
        Ah = ctxh + (size_t)s * 131072; Al = ctxl + (size_t)s * 131072;
        lda = 512; K = 512;
        Bh = wo1c_hi; Bl = wo1c_lo; bias = b_o1; C = octx;
    }

    __shared__ __align__(16) unsigned short sm[27648];
    f32x4 acc[4] = {};
    mfma_tile_64x128(Ah, Al, lda, b0, Bh, Bl, K, n0, sm, acc);

    const int lane = threadIdx.x & 63, wid = threadIdx.x >> 6;
    const int wr = wid >> 1, wc = wid & 1;
    const int l15 = lane & 15, g4 = (lane >> 4) * 4;
#pragma unroll
    for (int ni = 0; ni < 4; ++ni) {
        int col = n0 + wc * 64 + ni * 16 + l15;
        float bv = bias ? bias[col] : 0.f;
#pragma unroll
        for (int r = 0; r < 4; ++r) {
            int row = b0 + wr * 16 + g4 + r;
            C[(size_t)row * 1024 + col] = acc[ni][r] + bv;
        }
    }
}

// o-GEMM with folded LN epilogue; 1-D grid 32: bid = tm*8 + tn
__global__ __launch_bounds__(512, 2) void kb5_kernel(
    const unsigned short* __restrict__ hgh, const unsigned short* __restrict__ hgl,
    const unsigned short* __restrict__ w_hi, const unsigned short* __restrict__ w_lo,
    const float* __restrict__ uv, const float* __restrict__ octx,
    const float* __restrict__ mbuf, const float* __restrict__ isbuf,
    float* __restrict__ o)
{
    const int bid = blockIdx.x;
    const int tm = bid >> 3, tn = bid & 7;
    const int b0 = tm * 64, n0 = tn * 128;

    __shared__ __align__(16) unsigned short sm[27648];
    f32x4 acc[4] = {};
    mfma_tile_64x128(hgh, hgl, 1024, b0, w_hi, w_lo, 1024, n0, sm, acc);

    const int lane = threadIdx.x & 63, wid = threadIdx.x >> 6;
    const int wr = wid >> 1, wc = wid & 1;
    const int l15 = lane & 15, g4 = (lane >> 4) * 4;
#pragma unroll
    for (int ni = 0; ni < 4; ++ni) {
        int col = n0 + wc * 64 + ni * 16 + l15;
        float u = uv[col], vb = uv[1024 + col];
#pragma unroll
        for (int r = 0; r < 4; ++r) {
            int row = b0 + wr * 16 + g4 + r;
            float m = mbuf[row], is = isbuf[row];
            float v = (acc[ni][r] - m * u) * is + vb + octx[(size_t)row * 1024 + col];
            o[(size_t)row * 1024 + col] = fmaxf(v, 0.f);
        }
    }
}

// GRU combine + LN stats; writes h fp32 in-place + split h + split hg
__global__ void gru_ln2_kernel(const float* __restrict__ g6,
                               const float* __restrict__ b_ih, const float* __restrict__ b_hh,
                               float* __restrict__ h, const float* __restrict__ ln_g,
                               unsigned short* __restrict__ hh, unsigned short* __restrict__ hl,
                               unsigned short* __restrict__ hgh, unsigned short* __restrict__ hgl,
                               float* __restrict__ mbuf, float* __restrict__ isbuf)
{
    __shared__ float ls[4], lq[4];
    int b = blockIdx.x, tid = threadIdx.x;
    float s = 0.f, q = 0.f;
#pragma unroll
    for (int jj = 0; jj < 4; ++jj) {
        int j = jj * 256 + tid;
        size_t base = (size_t)b * 1024 + j;
        float xr = g6[0 * (size_t)SZ + base] + b_ih[j];
        float xz = g6[1 * (size_t)SZ + base] + b_ih[1024 + j];
        float xn = g6[2 * (size_t)SZ + base] + b_ih[2048 + j];
        float hr = g6[3 * (size_t)SZ + base] + b_hh[j];
        float hz = g6[4 * (size_t)SZ + base] + b_hh[1024 + j];
        float hn = g6[5 * (size_t)SZ + base] + b_hh[2048 + j];
        float r = 1.f / (1.f + expf(-(xr + hr)));
        float z = 1.f / (1.f + expf(-(xz + hz)));
        float nn = tanhf(xn + r * hn);
        float ho = h[base];
        float hv = (1.f - z) * nn + z * ho;
        h[base] = hv;
        unsigned short a, c;
        split2(hv, a, c); hh[base] = a; hl[base] = c;
        float hgv = hv * ln_g[j];
        split2(hgv, a, c); hgh[base] = a; hgl[base] = c;
        s += hv; q += hv * hv;
    }
    for (int off = 32; off; off >>= 1) {
        s += __shfl_down(s, off);
        q += __shfl_down(q, off);
    }
    int lane = tid & 63, w = tid >> 6;
    if (lane == 0) { ls[w] = s; lq[w] = q; }
    __syncthreads();
    if (tid == 0) {
        float S = ls[0] + ls[1] + ls[2] + ls[3];
        float Q = lq[0] + lq[1] + lq[2] + lq[3];
        float m = S * (1.f / 1024.f);
        mbuf[b] = m;
        isbuf[b] = rsqrtf(Q * (1.f / 1024.f) - m * m + 1e-5f);
    }
}

// logits + argmax + next-x build + ctx split; 64 blocks x 256 thr, 4 rows each
__global__ void kc2_kernel(const float* __restrict__ o, const float* __restrict__ Wo2t,
                           const float* __restrict__ b_o2, const float* __restrict__ cin,
                           const float* __restrict__ bpart, const float* __restrict__ ctx,
                           unsigned short* __restrict__ xh, unsigned short* __restrict__ xl,
                           unsigned short* __restrict__ ctxh, unsigned short* __restrict__ ctxl,
                           int* __restrict__ prev, float* __restrict__ out, int t)
{
    __shared__ __align__(16) float os[4][1024];
    __shared__ float red[4][4][64];
    __shared__ int sidx[4];
    const int b0 = blockIdx.x * 4, tid = threadIdx.x;

#pragma unroll
    for (int i = 0; i < 4; ++i) {
        int f = tid + i * 256;             // float4 index, 0..1023
        int r = f >> 8, c4 = (f & 255) << 2;
        *(float4*)&os[r][c4] = *(const float4*)(o + (size_t)(b0 + r) * 1024 + c4);
    }
    __syncthreads();

    {
        int n = tid & 63, seg = tid >> 6;
        float p0 = 0.f, p1 = 0.f, p2 = 0.f, p3 = 0.f;
        int k0 = seg * 256;
        for (int k = k0; k < k0 + 256; ++k) {
            float w = Wo2t[(size_t)k * 64 + n];
            p0 += os[0][k] * w; p1 += os[1][k] * w;
            p2 += os[2][k] * w; p3 += os[3][k] * w;
        }
        red[0][seg][n] = p0; red[1][seg][n] = p1;
        red[2][seg][n] = p2; red[3][seg][n] = p3;
    }
    __syncthreads();

    {
        int r = tid >> 6, n = tid & 63;
        float lg = red[r][0][n] + red[r][1][n] + red[r][2][n] + red[r][3][n] + b_o2[n];
        out[(size_t)(b0 + r) * (TT * 64) + t * 64 + n] = lg;
        float v = lg; int idx = n;
        for (int off = 32; off; off >>= 1) {
            float ov = __shfl_xor(v, off);
            int oi = __shfl_xor(idx, off);
            if (ov > v || (ov == v && oi < idx)) { v = ov; idx = oi; }
        }
        if (n == 0) { prev[b0 + r] = idx; sidx[r] = idx; }
    }
    __syncthreads();

    if (t + 1 < TT) {
#pragma unroll
        for (int i = 0; i < 16; ++i) {
            int idx = tid + i * 256;       // 0..4095
            int r = idx >> 10, j = idx & 1023;
            float v = fmaxf(cin[(size_t)(b0 + r) * 1024 + j] +
                            bpart[(size_t)sidx[r] * 1024 + j], 0.f);
            unsigned short h, l;
            split2(v, h, l);
            xh[(size_t)(b0 + r) * 1024 + j] = h;
            xl[(size_t)(b0 + r) * 1024 + j] = l;
        }
    }
    if (t + 2 < TT) {
        int slot = t & 1;
#pragma unroll
        for (int i = 0; i < 8; ++i) {
            int idx = tid + i * 256;       // 0..2047
            int r = idx >> 9, j = idx & 511;
            float v = ctx[(size_t)(b0 + r) * LDA_CTX + (t + 2) * 512 + j];
            unsigned short h, l;
            split2(v, h, l);
            ctxh[(size_t)slot * 131072 + (size_t)(b0 + r) * 512 + j] = h;
            ctxl[(size_t)slot * 131072 + (size_t)(b0 + r) * 512 + j] = l;
        }
    }
}

// -------------------- fallback fp32 step kernels (round 1) -----------------

__global__ void step_gemms_kernel(
    const float* __restrict__ x, const float* __restrict__ hBase,
    const float* __restrict__ ctx,
    const float* __restrict__ Wih, const float* __restrict__ Whh,
    const float* __restrict__ Win, const float* __restrict__ Wo1,
    const float* __restrict__ b_in, const float* __restrict__ b_o1,
    float* __restrict__ g6, float* __restrict__ cinBase, float* __restrict__ octx,
    int t)
{
    __shared__ __align__(16) float At[16 * TS];
    __shared__ __align__(16) float Wt[16 * TS];
    float acc[4][4] = {};
    const int z = blockIdx.z, b0 = blockIdx.x * 64, n0 = blockIdx.y * 64;
    const float *A, *W, *bias = nullptr;
    float* C;
    int lda, ldw, K;
    if (z < 6) {
        int g = z % 3, s = z / 3;
        A = s ? (hBase + (size_t)(t & 1) * SZ) : x;
        lda = 1024;
        W = (s ? Whh : Wih) + (size_t)(g * 1024) * 1024;
        ldw = 1024; K = 1024;
        C = g6 + (size_t)z * SZ;
    } else if (z == 6) {
        if (t + 1 >= TT) return;
        A = ctx + (size_t)(t + 1) * 512; lda = LDA_CTX;
        W = Win; ldw = 1024; K = 512; bias = b_in;
        C = cinBase + (size_t)((t + 1) & 1) * SZ;
    } else {
        A = ctx + (size_t)t * 512; lda = LDA_CTX;
        W = Wo1 + 1024; ldw = 1536; K = 512; bias = b_o1;
        C = octx;
    }
    gemm_tile64(A, lda, 256, b0, W, ldw, n0, K, At, Wt, acc);
    int tx = threadIdx.x & 15, ty = threadIdx.x >> 4;
#pragma unroll
    for (int i = 0; i < 4; ++i) {
        int b = b0 + ty * 4 + i;
#pragma unroll
        for (int j = 0; j < 4; ++j) {
            int n = n0 + tx * 4 + j;
            float v = acc[i][j];
            if (bias) v += bias[n];
            C[(size_t)b * 1024 + n] = v;
        }
    }
}

__global__ void kb_kernel(const float* __restrict__ hg, const float* __restrict__ Wo1,
                          const float* __restrict__ uv, const float* __restrict__ octx,
                          const float* __restrict__ mbuf, const float* __restrict__ isbuf,
                          float* __restrict__ o)
{
    __shared__ __align__(16) float At[16 * TS];
    __shared__ __align__(16) float Wt[16 * TS];
    float acc[2][4] = {};
    const int b0 = blockIdx.x * 32, n0 = blockIdx.y * 64;
    const int tid = threadIdx.x, tx = tid & 15, ty = tid >> 4;
    const int r = tid >> 2, c0 = (tid & 3) << 2;
    for (int k0 = 0; k0 < 1024; k0 += 16) {
        float4 av = make_float4(0.f, 0.f, 0.f, 0.f);
        if (r < 32) av = *(const float4*)(hg + (size_t)(b0 + r) * 1024 + k0 + c0);
        float4 wv = *(const float4*)(Wo1 + (size_t)(n0 + r) * 1536 + k0 + c0);
        __syncthreads();
        At[(c0+0)*TS + r] = av.x; At[(c0+1)*TS + r] = av.y;
        At[(c0+2)*TS + r] = av.z; At[(c0+3)*TS + r] = av.w;
        Wt[(c0+0)*TS + r] = wv.x; Wt[(c0+1)*TS + r] = wv.y;
        Wt[(c0+2)*TS + r] = wv.z; Wt[(c0+3)*TS + r] = wv.w;
        __syncthreads();
#pragma unroll
        for (int kk = 0; kk < 16; ++kk) {
            float2 a = *(const float2*)(At + kk*TS + ty*2);
            float4 w = *(const float4*)(Wt + kk*TS + tx*4);
            acc[0][0] += a.x*w.x; acc[0][1] += a.x*w.y; acc[0][2] += a.x*w.z; acc[0][3] += a.x*w.w;
            acc[1][0] += a.y*w.x; acc[1][1] += a.y*w.y; acc[1][2] += a.y*w.z; acc[1][3] += a.y*w.w;
        }
    }
#pragma unroll
    for (int i = 0; i < 2; ++i) {
        int b = b0 + ty * 2 + i;
        float m = mbuf[b], is = isbuf[b];
#pragma unroll
        for (int j = 0; j < 4; ++j) {
            int n = n0 + tx * 4 + j;
            float v = (acc[i][j] - m * uv[n]) * is + uv[1024 + n] + octx[(size_t)b * 1024 + n];
            o[(size_t)b * 1024 + n] = fmaxf(v, 0.f);
        }
    }
}

__global__ void gru_ln_kernel(const float* __restrict__ g6,
                              const float* __restrict__ b_ih, const float* __restrict__ b_hh,
                              float* __restrict__ hBase, const float* __restrict__ ln_g,
                              float* __restrict__ hg, float* __restrict__ mbuf,
                              float* __restrict__ isbuf, int t)
{
    __shared__ float rs[256], rq[256];
    int b = blockIdx.x, tid = threadIdx.x;
    const float* hc = hBase + (size_t)(t & 1) * SZ + (size_t)b * 1024;
    float* hnx = hBase + (size_t)((t + 1) & 1) * SZ + (size_t)b * 1024;
    float s = 0.f, q = 0.f;
#pragma unroll
    for (int jj = 0; jj < 4; ++jj) {
        int j = jj * 256 + tid;
        size_t base = (size_t)b * 1024 + j;
        float xr = g6[0 * (size_t)SZ + base] + b_ih[j];
        float xz = g6[1 * (size_t)SZ + base] + b_ih[1024 + j];
        float xn = g6[2 * (size_t)SZ + base] + b_ih[2048 + j];
        float hr = g6[3 * (size_t)SZ + base] + b_hh[j];
        float hz = g6[4 * (size_t)SZ + base] + b_hh[1024 + j];
        float hn = g6[5 * (size_t)SZ + base] + b_hh[2048 + j];
        float r = 1.f / (1.f + expf(-(xr + hr)));
        float z = 1.f / (1.f + expf(-(xz + hz)));
        float nn = tanhf(xn + r * hn);
        float ho = hc[j];
        float hv = (1.f - z) * nn + z * ho;
        hnx[j] = hv;
        hg[base] = hv * ln_g[j];
        s += hv; q += hv * hv;
    }
    rs[tid] = s; rq[tid] = q;
    __syncthreads();
    for (int st = 128; st; st >>= 1) {
        if (tid < st) { rs[tid] += rs[tid + st]; rq[tid] += rq[tid + st]; }
        __syncthreads();
    }
    if (tid == 0) {
        float m = rs[0] * (1.f / 1024.f);
        float var = rq[0] * (1.f / 1024.f) - m * m;
        mbuf[b] = m;
        isbuf[b] = rsqrtf(var + 1e-5f);
    }
}

__global__ void kc_kernel(const float* __restrict__ o, const float* __restrict__ Wo2t,
                          const float* __restrict__ b_o2, const float* __restrict__ cinBase,
                          const float* __restrict__ bpart, float* __restrict__ x,
                          int* __restrict__ prev, float* __restrict__ out, int t)
{
    __shared__ __align__(16) float os[1024];
    __shared__ float red[4][64];
    __shared__ int sidx;
    int b = blockIdx.x, tid = threadIdx.x;
    const float* orow = o + (size_t)b * 1024;
    *(float4*)&os[tid * 4] = *(const float4*)&orow[tid * 4];
    __syncthreads();
    int n = tid & 63, seg = tid >> 6;
    float p = 0.f;
    int k0 = seg * 256;
#pragma unroll 8
    for (int k = 0; k < 256; ++k) p += os[k0 + k] * Wo2t[(size_t)(k0 + k) * 64 + n];
    red[seg][n] = p;
    __syncthreads();
    if (tid < 64) {
        float lg = red[0][tid] + red[1][tid] + red[2][tid] + red[3][tid] + b_o2[tid];
        out[((size_t)b * TT + t) * 64 + tid] = lg;
        float v = lg; int idx = tid;
        for (int off = 32; off; off >>= 1) {
            float ov = __shfl_xor(v, off);
            int oi = __shfl_xor(idx, off);
            if (ov > v || (ov == v && oi < idx)) { v = ov; idx = oi; }
        }
        if (tid == 0) { prev[b] = idx; sidx = idx; }
    }
    __syncthreads();
    if (t + 1 < TT) {
        int pb = sidx;
        const float* cn = cinBase + (size_t)((t + 1) & 1) * SZ + (size_t)b * 1024;
        const float* bp = bpart + (size_t)pb * 1024;
#pragma unroll
        for (int jj = 0; jj < 4; ++jj) {
            int j = jj * 256 + tid;
            x[(size_t)b * 1024 + j] = fmaxf(cn[j] + bp[j], 0.f);
        }
    }
}

// ---------------------------------------------------------------------------

extern "C" void kernel_launch(void* const* d_in, const int* in_sizes, int n_in,
                              void* d_out, int out_size, void* d_ws, size_t ws_size,
                              hipStream_t stream)
{
    const float* ctx    = (const float*)d_in[0];
    const int*   bh     = (const int*)d_in[1];
    const float* be     = (const float*)d_in[2];
    const float* W_in   = (const float*)d_in[3];
    const float* b_in   = (const float*)d_in[4];
    const float* W_init = (const float*)d_in[5];
    const float* b_init = (const float*)d_in[6];
    const float* W_ih   = (const float*)d_in[7];
    const float* b_ih   = (const float*)d_in[8];
    const float* W_hh   = (const float*)d_in[9];
    const float* b_hh   = (const float*)d_in[10];
    const float* ln_g   = (const float*)d_in[11];
    const float* ln_b   = (const float*)d_in[12];
    const float* W_o1   = (const float*)d_in[13];
    const float* b_o1   = (const float*)d_in[14];
    const float* W_o2   = (const float*)d_in[15];
    const float* b_o2   = (const float*)d_in[16];
    float* out = (float*)d_out;
    float* ws  = (float*)d_ws;

    const bool mfma_path = (ws_size >= 49830000ull);

    if (mfma_path) {
        float* A0    = ws;                 // setup only; aliases obuf
        float* obuf  = ws;
        float* hbuf  = ws + 262144;        // h fp32 (in-place)
        float* cin   = ws + 524288;
        float* octx  = ws + 786432;
        float* g6    = ws + 1048576;       // 6 slots
        float* bpart = ws + 2621440;       // 64x1024
        float* uvv   = ws + 2686976;       // 2x1024
        float* gb    = ws + 2689024;       // 2x1024
        float* Wo2t  = ws + 2691072;       // 1024x64
        float* mbuf  = ws + 2756608;
        float* isbuf = ws + 2756864;
        int*   prev  = (int*)(ws + 2757120);
        unsigned short* bf = (unsigned short*)(ws + 2757632);
        unsigned short* wih_hi  = bf;
        unsigned short* wih_lo  = bf + 3145728;
        unsigned short* whh_hi  = bf + 6291456;
        unsigned short* whh_lo  = bf + 9437184;
        unsigned short* wo1k_hi = bf + 12582912;
        unsigned short* wo1k_lo = bf + 13631488;
        unsigned short* wo1c_hi = bf + 14680064;
        unsigned short* wo1c_lo = bf + 15204352;
        unsigned short* wcin_hi = bf + 15728640;
        unsigned short* wcin_lo = bf + 16252928;
        unsigned short* xh   = bf + 16777216;
        unsigned short* xl   = bf + 17039360;
        unsigned short* hh   = bf + 17301504;
        unsigned short* hl   = bf + 17563648;
        unsigned short* hgh  = bf + 17825792;
        unsigned short* hgl  = bf + 18087936;
        unsigned short* ctxh = bf + 18350080;   // [2][256][512]
        unsigned short* ctxl = bf + 18612224;

        // ---- setup ----
        pre0_kernel<<<256, 512, 0, stream>>>(ctx, bh, be, A0, prev);
        copy_gb_kernel<<<8, 256, 0, stream>>>(ln_g, ln_b, gb);
        wo2t_kernel<<<256, 256, 0, stream>>>(W_o2, Wo2t);
        gemm64_kernel<<<dim3(4, 16), 256, 0, stream>>>(A0, 1024, 256, W_init, 1024, 1024,
                                                       b_init, hbuf, 1024, 1);
        gemm64_kernel<<<dim3(1, 16), 256, 0, stream>>>(be, 512, 64, W_in + 512, 1024, 512,
                                                       nullptr, bpart, 1024, 0);
        gemm64_kernel<<<dim3(1, 16), 256, 0, stream>>>(gb, 1024, 2, W_o1, 1536, 1024,
                                                       nullptr, uvv, 1024, 0);
        gemm64_kernel<<<dim3(4, 16), 256, 0, stream>>>(ctx, LDA_CTX, 256, W_in, 1024, 512,
                                                       b_in, cin, 1024, 0);
        xbuild0s_kernel<<<256, 256, 0, stream>>>(cin, bpart, prev, xh, xl);
        // weight splits
        wsplit_kernel<<<12288, 256, 0, stream>>>(W_ih, 1024, 0, 3072, 1024, wih_hi, wih_lo);
        wsplit_kernel<<<12288, 256, 0, stream>>>(W_hh, 1024, 0, 3072, 1024, whh_hi, whh_lo);
        wsplit_kernel<<<4096, 256, 0, stream>>>(W_o1, 1536, 0, 1024, 1024, wo1k_hi, wo1k_lo);
        wsplit_kernel<<<2048, 256, 0, stream>>>(W_o1, 1536, 1024, 1024, 512, wo1c_hi, wo1c_lo);
        wsplit_kernel<<<2048, 256, 0, stream>>>(W_in, 1024, 0, 1024, 512, wcin_hi, wcin_lo);
        // activation splits: h0, ctx slices 0 and 1
        wsplit_kernel<<<1024, 256, 0, stream>>>(hbuf, 1024, 0, 256, 1024, hh, hl);
        wsplit_kernel<<<512, 256, 0, stream>>>(ctx, LDA_CTX, 0, 256, 512, ctxh, ctxl);
        wsplit_kernel<<<512, 256, 0, stream>>>(ctx, LDA_CTX, 512, 256, 512,
                                               ctxh + 131072, ctxl + 131072);

        // ---- recurrence ----
        for (int t = 0; t < TT; ++t) {
            gates5_kernel<<<256, 512, 0, stream>>>(
                xh, xl, hh, hl, ctxh, ctxl,
                wih_hi, wih_lo, whh_hi, whh_lo, wcin_hi, wcin_lo, wo1c_hi, wo1c_lo,
                b_in, b_o1, g6, cin, octx, t);
            gru_ln2_kernel<<<256, 256, 0, stream>>>(g6, b_ih, b_hh, hbuf, ln_g,
                                                    hh, hl, hgh, hgl, mbuf, isbuf);
            kb5_kernel<<<32, 512, 0, stream>>>(hgh, hgl, wo1k_hi, wo1k_lo,
                                               uvv, octx, mbuf, isbuf, obuf);
            kc2_kernel<<<64, 256, 0, stream>>>(obuf, Wo2t, b_o2, cin, bpart, ctx,
                                               xh, xl, ctxh, ctxl, prev, out, t);
        }
    } else {
        // ---- fallback: round-1 fp32 path ----
        float* A0    = ws;
        float* hbuf  = ws + 262144;
        float* hg    = ws + 786432;
        float* x     = ws + 1048576;
        float* cin   = ws + 1310720;
        float* octx  = ws + 1835008;
        float* g6    = ws + 2097152;
        float* obuf  = ws + 3670016;
        float* bpart = ws + 3932160;
        float* uvv   = ws + 3997696;
        float* gb    = ws + 3999744;
        float* Wo2t  = ws + 4001792;
        float* mbuf  = ws + 4067328;
        float* isbuf = ws + 4067584;
        int*   prev  = (int*)(ws + 4067840);

        pre0_kernel<<<256, 512, 0, stream>>>(ctx, bh, be, A0, prev);
        copy_gb_kernel<<<8, 256, 0, stream>>>(ln_g, ln_b, gb);
        wo2t_kernel<<<256, 256, 0, stream>>>(W_o2, Wo2t);
        gemm64_kernel<<<dim3(4, 16), 256, 0, stream>>>(A0, 1024, 256, W_init, 1024, 1024,
                                                       b_init, hbuf, 1024, 1);
        gemm64_kernel<<<dim3(1, 16), 256, 0, stream>>>(be, 512, 64, W_in + 512, 1024, 512,
                                                       nullptr, bpart, 1024, 0);
        gemm64_kernel<<<dim3(1, 16), 256, 0, stream>>>(gb, 1024, 2, W_o1, 1536, 1024,
                                                       nullptr, uvv, 1024, 0);
        gemm64_kernel<<<dim3(4, 16), 256, 0, stream>>>(ctx, LDA_CTX, 256, W_in, 1024, 512,
                                                       b_in, cin, 1024, 0);
        xbuild0_kernel<<<256, 256, 0, stream>>>(cin, bpart, prev, x);

        for (int t = 0; t < TT; ++t) {
            step_gemms_kernel<<<dim3(4, 16, 8), 256, 0, stream>>>(
                x, hbuf, ctx, W_ih, W_hh, W_in, W_o1, b_in, b_o1, g6, cin, octx, t);
            gru_ln_kernel<<<256, 256, 0, stream>>>(g6, b_ih, b_hh, hbuf, ln_g, hg,
                                                   mbuf, isbuf, t);
            kb_kernel<<<dim3(8, 16), 256, 0, stream>>>(hg, W_o1, uvv, octx, mbuf, isbuf, obuf);
            kc_kernel<<<256, 256, 0, stream>>>(obuf, Wo2t, b_o2, cin, bpart, x, prev, out, t);
        }
    }
}